// Round 15
// baseline (289.566 us; speedup 1.0000x reference)
//
#include <hip/hip_runtime.h>

#define H 1024
#define F 2048
#define NE 8
#define T_TOK 8192

#define BM 128
#define BN 128
#define BK 64

typedef __bf16 bf16x8 __attribute__((ext_vector_type(8)));
typedef float floatx4 __attribute__((ext_vector_type(4)));

__device__ __forceinline__ unsigned short f2bf(float f) {
    unsigned int u = __builtin_bit_cast(unsigned int, f);
    u = (u + 0x7fffu + ((u >> 16) & 1u)) >> 16;
    return (unsigned short)u;
}
__device__ __forceinline__ float bf2f(unsigned short u) {
    unsigned int x = ((unsigned int)u) << 16;
    return __builtin_bit_cast(float, x);
}

// async 16B global -> LDS (linear dest: wave-uniform base + lane*16)
__device__ __forceinline__ void gload16(const unsigned short* g, void* l) {
    __builtin_amdgcn_global_load_lds(
        (const __attribute__((address_space(1))) unsigned int*)g,
        (__attribute__((address_space(3))) unsigned int*)l,
        16, 0, 0);
}

// transpose+convert one 64x64 tile: in[R][C] fp32 -> out[C][R] bf16 (smem-overlaid tile)
__device__ __forceinline__ void transpose_tile(const float* __restrict__ in,
                                               unsigned short* __restrict__ out,
                                               int R, int C, int r0, int c0,
                                               int tid, char* smem) {
    float (*tile)[65] = (float(*)[65])smem;
    int tc = tid & 63, tr = tid >> 6;
#pragma unroll
    for (int j = 0; j < 16; ++j)
        tile[tr + j * 4][tc] = in[(size_t)(r0 + tr + j * 4) * C + c0 + tc];
    __syncthreads();
#pragma unroll
    for (int j = 0; j < 4; ++j) {
        int idx = j * 256 + tid;
        int c = idx >> 4;
        int r4 = (idx & 15) * 4;
        ushort4 o;
        o.x = f2bf(tile[r4 + 0][c]);
        o.y = f2bf(tile[r4 + 1][c]);
        o.z = f2bf(tile[r4 + 2][c]);
        o.w = f2bf(tile[r4 + 3][c]);
        *(ushort4*)(out + (size_t)(c0 + c) * R + r0 + r4) = o;
    }
}

// ============ prep: fused {w1 transpose | w2 transpose | gate+cvt} ======
__global__ __launch_bounds__(256) void prep_kernel(const float* __restrict__ x,
                                                   const float* __restrict__ gw,
                                                   const float* __restrict__ gb,
                                                   const float* __restrict__ w1,
                                                   const float* __restrict__ w2,
                                                   unsigned short* __restrict__ xb,
                                                   unsigned short* __restrict__ w1t,
                                                   unsigned short* __restrict__ w2t,
                                                   int* __restrict__ top_i,
                                                   float* __restrict__ top_w) {
    __shared__ __align__(16) char smem[16704];   // 64x65 float tile
    __shared__ float wred[4][8];
    const int bid = blockIdx.x;
    const int tid = threadIdx.x;

    if (bid < 4096) {
        int z = bid >> 9, t9 = bid & 511;
        const size_t mat = (size_t)H * F;
        transpose_tile(w1 + (size_t)z * mat, w1t + (size_t)z * mat,
                       H, F, (t9 & 15) * 64, (t9 >> 4) * 64, tid, smem);
    } else if (bid < 8192) {
        int idx = bid - 4096;
        int z = idx >> 9, t9 = idx & 511;
        const size_t mat = (size_t)F * H;
        transpose_tile(w2 + (size_t)z * mat, w2t + (size_t)z * mat,
                       F, H, (t9 >> 4) * 64, (t9 & 15) * 64, tid, smem);
    } else {
        // gate: x fp32 -> xb bf16 + top-2 routing (1 token / block)
        const int t = bid - 8192;
        const float* xr = x + (size_t)t * H;
        float4 v = ((const float4*)xr)[tid];
        ushort4 o;
        o.x = f2bf(v.x); o.y = f2bf(v.y); o.z = f2bf(v.z); o.w = f2bf(v.w);
        ((ushort4*)(xb + (size_t)t * H))[tid] = o;

        float acc[8];
#pragma unroll
        for (int e = 0; e < 8; ++e) acc[e] = 0.f;
        const float4* g = (const float4*)(gw + (size_t)tid * 32);
#pragma unroll
        for (int r = 0; r < 4; ++r) {
            float xv = (r == 0) ? v.x : (r == 1) ? v.y : (r == 2) ? v.z : v.w;
            float4 g0 = g[r * 2], g1 = g[r * 2 + 1];
            acc[0] += xv * g0.x; acc[1] += xv * g0.y;
            acc[2] += xv * g0.z; acc[3] += xv * g0.w;
            acc[4] += xv * g1.x; acc[5] += xv * g1.y;
            acc[6] += xv * g1.z; acc[7] += xv * g1.w;
        }
#pragma unroll
        for (int m = 32; m >= 1; m >>= 1) {
#pragma unroll
            for (int e = 0; e < 8; ++e) acc[e] += __shfl_xor(acc[e], m, 64);
        }
        const int lane = tid & 63, w = tid >> 6;
        if (lane == 0) {
#pragma unroll
            for (int e = 0; e < 8; ++e) wred[w][e] = acc[e];
        }
        __syncthreads();
        if (tid == 0) {
            float lg[8];
#pragma unroll
            for (int e = 0; e < 8; ++e)
                lg[e] = wred[0][e] + wred[1][e] + wred[2][e] + wred[3][e] + gb[e];
            int i1 = 0; float v1 = lg[0];
#pragma unroll
            for (int e = 1; e < 8; ++e) { if (lg[e] > v1) { v1 = lg[e]; i1 = e; } }
            int i2 = -1; float v2 = -1e30f;
#pragma unroll
            for (int e = 0; e < 8; ++e) { if (e != i1 && lg[e] > v2) { v2 = lg[e]; i2 = e; } }
            float ed = expf(v2 - v1);
            top_i[t * 2] = i1; top_i[t * 2 + 1] = i2;
            top_w[t * 2] = 1.f / (1.f + ed);
            top_w[t * 2 + 1] = ed / (1.f + ed);
        }
    }
}

// ---------------- gating phase B: deterministic compaction + inverse map ----------------
__global__ __launch_bounds__(1024) void compact_kernel(const int* __restrict__ top_i,
                                                       const float* __restrict__ top_w,
                                                       int* __restrict__ counts,
                                                       int* __restrict__ btok,
                                                       int* __restrict__ inv) {
    const int e = blockIdx.x;
    const int tid = threadIdx.x;
    const int lane = tid & 63, w = tid >> 6;
    __shared__ int wsums[16];
    int base = 0;
    for (int c = 0; c < T_TOK / 1024; ++c) {
        int t = c * 1024 + tid;
        int i1 = top_i[t * 2], i2 = top_i[t * 2 + 1];
        bool f1 = (i1 == e), f2 = (i2 == e);
        bool f = f1 || f2;
        unsigned long long m = __ballot(f);
        int mypos = __popcll(m & ((1ull << lane) - 1ull));
        if (lane == 0) wsums[w] = __popcll(m);
        __syncthreads();
        int wpre = 0, tot = 0;
#pragma unroll
        for (int i = 0; i < 16; ++i) { int s = wsums[i]; if (i < w) wpre += s; tot += s; }
        if (f) {
            int pos = base + wpre + mypos;
            btok[e * T_TOK + pos] = t;
            inv[t * 2 + (f1 ? 0 : 1)] = (e << 16) | pos;
        }
        base += tot;
        __syncthreads();
    }
    if (tid == 0) counts[e] = base;
}

// ============ FFN layer 1 (R4-proven): 128x128xBK64 dbuf, prefetch-under-compute ======
__global__ __launch_bounds__(256, 2) void ffn1_kernel(const unsigned short* __restrict__ xb,
                                                      const unsigned short* __restrict__ w1t,
                                                      const float* __restrict__ b1,
                                                      const int* __restrict__ counts,
                                                      const int* __restrict__ btok,
                                                      unsigned short* __restrict__ hbuf) {
    const int orig = blockIdx.x;                 // grid = 8192
    const int logical = (orig & 7) * 1024 + (orig >> 3);
    const int e = logical >> 10;
    const int rem = logical & 1023;
    const int by = rem >> 4;
    const int bx = rem & 15;
    const int cnt = counts[e];
    if (by * BM >= cnt) return;
    const int n0 = bx * BN;
    int off_e = 0;
#pragma unroll
    for (int i = 0; i < NE; ++i) off_e += (i < e) ? counts[i] : 0;

    __shared__ __align__(16) char smem[65536];

    const int tid = threadIdx.x;
    const int lane = tid & 63, wid = tid >> 6;
    const int csrc = (lane & 7) ^ (lane >> 3);
    const int rloc = lane >> 3;

    int tokA[4];
#pragma unroll
    for (int i = 0; i < 4; ++i) {
        int r = wid * 32 + i * 8 + rloc;
        tokA[i] = btok[e * T_TOK + min(by * BM + r, cnt - 1)];
    }

    floatx4 acc[4][4];
#pragma unroll
    for (int i = 0; i < 4; ++i)
#pragma unroll
        for (int j = 0; j < 4; ++j)
#pragma unroll
            for (int r = 0; r < 4; ++r) acc[i][j][r] = 0.f;

    const int wm = (wid >> 1) * 64, wn = (wid & 1) * 64;

    auto stage = [&](int boff, int kt) {
        const int k0 = kt * BK;
#pragma unroll
        for (int i = 0; i < 4; ++i) {
            int seg = wid * 32 + i * 8;
            gload16(xb + (size_t)tokA[i] * H + k0 + csrc * 8, smem + boff + seg * 128);
            gload16(w1t + ((size_t)e * F + n0 + seg + rloc) * H + k0 + csrc * 8,
                    smem + boff + 16384 + seg * 128);
        }
    };

    const int NT = H / BK;  // 16
    stage(0, 0);
    int cur = 0;
    for (int kt = 0; kt < NT; ++kt) {
        const int boff = cur * 32768;
        __syncthreads();
        if (kt + 1 < NT) stage(boff ^ 32768, kt + 1);
#pragma unroll
        for (int kk = 0; kk < 2; ++kk) {
            bf16x8 af[4], bfr[4];
#pragma unroll
            for (int i = 0; i < 4; ++i) {
                int rA = wm + i * 16 + (lane & 15);
                af[i] = *(const bf16x8*)(smem + boff + rA * 128 + (((kk * 4 + (lane >> 4)) ^ (rA & 7)) * 16));
                int rB = wn + i * 16 + (lane & 15);
                bfr[i] = *(const bf16x8*)(smem + boff + 16384 + rB * 128 + (((kk * 4 + (lane >> 4)) ^ (rB & 7)) * 16));
            }
#pragma unroll
            for (int i = 0; i < 4; ++i)
#pragma unroll
                for (int j = 0; j < 4; ++j)
                    acc[i][j] = __builtin_amdgcn_mfma_f32_16x16x32_bf16(af[i], bfr[j], acc[i][j], 0, 0, 0);
        }
        cur ^= 1;
    }

#pragma unroll
    for (int i = 0; i < 4; ++i) {
        int mrow = wm + i * 16 + (lane >> 4) * 4;
#pragma unroll
        for (int r = 0; r < 4; ++r) {
            int mg = by * BM + mrow + r;
            if (mg < cnt) {
                size_t hrow = (size_t)(off_e + mg) * F;
#pragma unroll
                for (int j = 0; j < 4; ++j) {
                    int ng = n0 + wn + j * 16 + (lane & 15);
                    float v = acc[i][j][r] + b1[e * F + ng];
                    hbuf[hrow + ng] = f2bf(fmaxf(v, 0.f));
                }
            }
        }
    }
}

// ============ FFN layer 2: ring-4 BK=32 counted-vmcnt pipeline (no mid-loop drain) =====
// Ring of 4 x 16KB slots (A[128][32] + B[128][32] bf16). Stage tile t+3 into slot
// (t+3)&3 = (t-1)&3 (freed by the top barrier). vmcnt(12) = own 4 loads of tile t
// landed (flight = 3 tiles); tail 8->4->0. 64KB LDS -> 2 blocks/CU preserved.
__global__ __launch_bounds__(256, 2) void ffn2_kernel(const unsigned short* __restrict__ hbuf,
                                                      const unsigned short* __restrict__ w2t,
                                                      const float* __restrict__ b2,
                                                      const int* __restrict__ counts,
                                                      unsigned short* __restrict__ yc) {
    const int orig = blockIdx.x;                 // grid = 4096
    const int logical = (orig & 7) * 512 + (orig >> 3);
    const int e = logical >> 9;
    const int rem = logical & 511;
    const int by = rem >> 3;
    const int bx = rem & 7;
    const int cnt = counts[e];
    if (by * BM >= cnt) return;
    const int n0 = bx * BN;
    int off_e = 0;
#pragma unroll
    for (int i = 0; i < NE; ++i) off_e += (i < e) ? counts[i] : 0;

    __shared__ __align__(16) char smem[65536];   // 4 slots x 16KB

    const int tid = threadIdx.x;
    const int lane = tid & 63, wid = tid >> 6;
    const int rloc4 = lane >> 2;                 // 0..15 (64B rows, 4 lanes/row)
    const int csrc = (lane & 3) ^ (rloc4 & 3);   // pre-swizzled source chunk
    const int wm = (wid >> 1) * 64, wn = (wid & 1) * 64;

    int arow[2];
#pragma unroll
    for (int s = 0; s < 2; ++s) {
        int r = wid * 32 + s * 16 + rloc4;
        arow[s] = off_e + min(by * BM + r, cnt - 1);
    }

    floatx4 acc[4][4];
#pragma unroll
    for (int i = 0; i < 4; ++i)
#pragma unroll
        for (int j = 0; j < 4; ++j)
#pragma unroll
            for (int r = 0; r < 4; ++r) acc[i][j][r] = 0.f;

    auto stage = [&](int kt, int slot) {         // 4 gload16 / wave
        const int k0 = kt * 32;
        char* base = smem + slot * 16384;
#pragma unroll
        for (int s = 0; s < 2; ++s) {
            gload16(hbuf + (size_t)arow[s] * F + k0 + csrc * 8,
                    base + (wid * 32 + s * 16) * 64);
            gload16(w2t + ((size_t)e * H + n0 + wid * 32 + s * 16 + rloc4) * F + k0 + csrc * 8,
                    base + 8192 + (wid * 32 + s * 16) * 64);
        }
    };

    const int NT = F / 32;  // 64
    stage(0, 0); stage(1, 1); stage(2, 2);       // 12 loads in flight
    const int q = lane >> 4;
#pragma unroll 1
    for (int t = 0; t < NT; ++t) {
        __builtin_amdgcn_s_barrier();            // all waves done reading slot (t-1)&3
        __builtin_amdgcn_sched_barrier(0);
        if (t + 3 < NT) stage(t + 3, (t + 3) & 3);
        if (t + 3 < NT)      asm volatile("s_waitcnt vmcnt(12)" ::: "memory");
        else if (t + 2 < NT) asm volatile("s_waitcnt vmcnt(8)" ::: "memory");
        else if (t + 1 < NT) asm volatile("s_waitcnt vmcnt(4)" ::: "memory");
        else                 asm volatile("s_waitcnt vmcnt(0)" ::: "memory");
        __builtin_amdgcn_s_barrier();            // everyone's tile-t loads landed
        __builtin_amdgcn_sched_barrier(0);

        const char* base = smem + (t & 3) * 16384;
        bf16x8 af[4], bfr[4];
#pragma unroll
        for (int i = 0; i < 4; ++i) {
            int rA = wm + i * 16 + (lane & 15);
            af[i] = *(const bf16x8*)(base + rA * 64 + ((q ^ (rA & 3)) * 16));
            int rB = wn + i * 16 + (lane & 15);
            bfr[i] = *(const bf16x8*)(base + 8192 + rB * 64 + ((q ^ (rB & 3)) * 16));
        }
        __builtin_amdgcn_s_setprio(1);
#pragma unroll
        for (int i = 0; i < 4; ++i)
#pragma unroll
            for (int j = 0; j < 4; ++j)
                acc[i][j] = __builtin_amdgcn_mfma_f32_16x16x32_bf16(af[i], bfr[j], acc[i][j], 0, 0, 0);
        __builtin_amdgcn_s_setprio(0);
        __builtin_amdgcn_sched_barrier(0);
    }

#pragma unroll
    for (int i = 0; i < 4; ++i) {
        int mrow = wm + i * 16 + (lane >> 4) * 4;
#pragma unroll
        for (int r = 0; r < 4; ++r) {
            int mg = by * BM + mrow + r;
            if (mg < cnt) {
                size_t yrow = (size_t)(off_e + mg) * H;
#pragma unroll
                for (int j = 0; j < 4; ++j) {
                    int ng = n0 + wn + j * 16 + (lane & 15);
                    yc[yrow + ng] = f2bf(acc[i][j][r] + b2[e * H + ng]);
                }
            }
        }
    }
}

// ---------------- combine: out[t] = w0*yc[slot0] + w1*yc[slot1], 4 tokens/block --------
__global__ __launch_bounds__(256) void combine_kernel(const unsigned short* __restrict__ yc,
                                                      const int* __restrict__ counts,
                                                      const int* __restrict__ inv,
                                                      const float* __restrict__ top_w,
                                                      float* __restrict__ out) {
    const int tid = threadIdx.x;
    int offs[NE];
    {
        int s = 0;
#pragma unroll
        for (int e = 0; e < NE; ++e) { offs[e] = s; s += counts[e]; }
    }
#pragma unroll
    for (int tk = 0; tk < 4; ++tk) {
        const int t = blockIdx.x * 4 + tk;
        int c0 = inv[2 * t], c1 = inv[2 * t + 1];
        float w0 = top_w[2 * t], w1 = top_w[2 * t + 1];
        size_t r0 = (size_t)(offs[c0 >> 16] + (c0 & 0xffff)) * H;
        size_t r1 = (size_t)(offs[c1 >> 16] + (c1 & 0xffff)) * H;
        int h = tid * 4;
        ushort4 a = *(const ushort4*)(yc + r0 + h);
        ushort4 b = *(const ushort4*)(yc + r1 + h);
        float4 o;
        o.x = w0 * bf2f(a.x) + w1 * bf2f(b.x);
        o.y = w0 * bf2f(a.y) + w1 * bf2f(b.y);
        o.z = w0 * bf2f(a.z) + w1 * bf2f(b.z);
        o.w = w0 * bf2f(a.w) + w1 * bf2f(b.w);
        *(float4*)(out + (size_t)t * H + h) = o;
    }
}

extern "C" void kernel_launch(void* const* d_in, const int* in_sizes, int n_in,
                              void* d_out, int out_size, void* d_ws, size_t ws_size,
                              hipStream_t stream) {
    (void)in_sizes; (void)n_in; (void)out_size; (void)ws_size;
    const float* x  = (const float*)d_in[0];
    const float* gw = (const float*)d_in[1];
    const float* gb = (const float*)d_in[2];
    const float* w1 = (const float*)d_in[3];
    const float* b1 = (const float*)d_in[4];
    const float* w2 = (const float*)d_in[5];
    const float* b2 = (const float*)d_in[6];
    float* out = (float*)d_out;

    char* ws = (char*)d_ws;
    unsigned short* w2t  = (unsigned short*)(ws);                        // 32 MB @ 0
    unsigned short* hbuf = (unsigned short*)(ws + (32ull << 20));        // 64 MB @ 32
    unsigned short* xb   = (unsigned short*)(ws + (96ull << 20));        // 16 MB @ 96
    unsigned short* w1t  = (unsigned short*)(ws + (112ull << 20));       // 32 MB @ 112 (ends 144)
    unsigned short* yc   = (unsigned short*)(ws + (96ull << 20));        // overlaps xb+w1t (dead after ffn1)
    char* small = ws + (144ull << 20);
    int*   btok   = (int*)(small);                                       // 256 KB
    int*   top_i  = (int*)(small + 0x80000);                             // 64 KB
    float* top_w  = (float*)(small + 0x90000);                           // 64 KB
    int*   inv    = (int*)(small + 0xA0000);                             // 64 KB
    int*   counts = (int*)(small + 0xB0000);

    prep_kernel<<<16384, 256, 0, stream>>>(x, gw, gb, w1, w2, xb, w1t, w2t, top_i, top_w);
    compact_kernel<<<NE, 1024, 0, stream>>>(top_i, top_w, counts, btok, inv);
    ffn1_kernel<<<8192, 256, 0, stream>>>(xb, w1t, b1, counts, btok, hbuf);
    ffn2_kernel<<<8 * 64 * NE, 256, 0, stream>>>(hbuf, w2t, b2, counts, yc);
    combine_kernel<<<T_TOK / 4, 256, 0, stream>>>(yc, counts, inv, top_w, out);
}

// Round 16
// 256.282 us; speedup vs baseline: 1.1299x; 1.1299x over previous
//
#include <hip/hip_runtime.h>

#define H 1024
#define F 2048
#define NE 8
#define T_TOK 8192

#define BM 128
#define BN 128
#define BK 64

typedef __bf16 bf16x8 __attribute__((ext_vector_type(8)));
typedef float floatx4 __attribute__((ext_vector_type(4)));

__device__ __forceinline__ unsigned short f2bf(float f) {
    unsigned int u = __builtin_bit_cast(unsigned int, f);
    u = (u + 0x7fffu + ((u >> 16) & 1u)) >> 16;
    return (unsigned short)u;
}
__device__ __forceinline__ float bf2f(unsigned short u) {
    unsigned int x = ((unsigned int)u) << 16;
    return __builtin_bit_cast(float, x);
}

// async 16B global -> LDS (linear dest: wave-uniform base + lane*16)
__device__ __forceinline__ void gload16(const unsigned short* g, void* l) {
    __builtin_amdgcn_global_load_lds(
        (const __attribute__((address_space(1))) unsigned int*)g,
        (__attribute__((address_space(3))) unsigned int*)l,
        16, 0, 0);
}

// transpose+convert one 64x64 tile (256 threads): in[R][C] fp32 -> out[C][R] bf16
__device__ __forceinline__ void transpose_tile(const float* __restrict__ in,
                                               unsigned short* __restrict__ out,
                                               int R, int C, int r0, int c0,
                                               int tid, char* smem) {
    float (*tile)[65] = (float(*)[65])smem;
    int tc = tid & 63, tr = tid >> 6;
#pragma unroll
    for (int j = 0; j < 16; ++j)
        tile[tr + j * 4][tc] = in[(size_t)(r0 + tr + j * 4) * C + c0 + tc];
    __syncthreads();
#pragma unroll
    for (int j = 0; j < 4; ++j) {
        int idx = j * 256 + tid;
        int c = idx >> 4;
        int r4 = (idx & 15) * 4;
        ushort4 o;
        o.x = f2bf(tile[r4 + 0][c]);
        o.y = f2bf(tile[r4 + 1][c]);
        o.z = f2bf(tile[r4 + 2][c]);
        o.w = f2bf(tile[r4 + 3][c]);
        *(ushort4*)(out + (size_t)(c0 + c) * R + r0 + r4) = o;
    }
}

// ---------------- gate: x fp32 -> xb bf16 + top-2 routing (1 token / block) ------------
__global__ __launch_bounds__(256) void gate_kernel(const float* __restrict__ x,
                                                   const float* __restrict__ gw,
                                                   const float* __restrict__ gb,
                                                   unsigned short* __restrict__ xb,
                                                   int* __restrict__ top_i,
                                                   float* __restrict__ top_w) {
    __shared__ float wred[4][8];
    const int t = blockIdx.x;
    const int tid = threadIdx.x;
    const float* xr = x + (size_t)t * H;
    float4 v = ((const float4*)xr)[tid];
    ushort4 o;
    o.x = f2bf(v.x); o.y = f2bf(v.y); o.z = f2bf(v.z); o.w = f2bf(v.w);
    ((ushort4*)(xb + (size_t)t * H))[tid] = o;

    float acc[8];
#pragma unroll
    for (int e = 0; e < 8; ++e) acc[e] = 0.f;
    const float4* g = (const float4*)(gw + (size_t)tid * 32);
#pragma unroll
    for (int r = 0; r < 4; ++r) {
        float xv = (r == 0) ? v.x : (r == 1) ? v.y : (r == 2) ? v.z : v.w;
        float4 g0 = g[r * 2], g1 = g[r * 2 + 1];
        acc[0] += xv * g0.x; acc[1] += xv * g0.y;
        acc[2] += xv * g0.z; acc[3] += xv * g0.w;
        acc[4] += xv * g1.x; acc[5] += xv * g1.y;
        acc[6] += xv * g1.z; acc[7] += xv * g1.w;
    }
#pragma unroll
    for (int m = 32; m >= 1; m >>= 1) {
#pragma unroll
        for (int e = 0; e < 8; ++e) acc[e] += __shfl_xor(acc[e], m, 64);
    }
    const int lane = tid & 63, w = tid >> 6;
    if (lane == 0) {
#pragma unroll
        for (int e = 0; e < 8; ++e) wred[w][e] = acc[e];
    }
    __syncthreads();
    if (tid == 0) {
        float lg[8];
#pragma unroll
        for (int e = 0; e < 8; ++e)
            lg[e] = wred[0][e] + wred[1][e] + wred[2][e] + wred[3][e] + gb[e];
        int i1 = 0; float v1 = lg[0];
#pragma unroll
        for (int e = 1; e < 8; ++e) { if (lg[e] > v1) { v1 = lg[e]; i1 = e; } }
        int i2 = -1; float v2 = -1e30f;
#pragma unroll
        for (int e = 0; e < 8; ++e) { if (e != i1 && lg[e] > v2) { v2 = lg[e]; i2 = e; } }
        float ed = expf(v2 - v1);
        top_i[t * 2] = i1; top_i[t * 2 + 1] = i2;
        top_w[t * 2] = 1.f / (1.f + ed);
        top_w[t * 2 + 1] = ed / (1.f + ed);
    }
}

// ======= compact (8 blocks) + w1 transpose (4096 blocks) fused: w1T rides idle CUs =====
__global__ __launch_bounds__(1024) void compact_w1t_kernel(const int* __restrict__ top_i,
                                                           const float* __restrict__ top_w,
                                                           int* __restrict__ counts,
                                                           int* __restrict__ btok,
                                                           int* __restrict__ inv,
                                                           const float* __restrict__ w1,
                                                           unsigned short* __restrict__ w1t) {
    __shared__ __align__(16) char smem[16704];
    __shared__ int wsums[16];
    const int tid = threadIdx.x;

    if (blockIdx.x >= 8) {
        // -------- w1 [H][F] -> w1t [F][H] (1024-thread 64x64 tile) --------
        const int idx = blockIdx.x - 8;
        const int z = idx >> 9, t9 = idx & 511;
        const size_t mat = (size_t)H * F;
        const float* ib = w1 + (size_t)z * mat;
        unsigned short* ob = w1t + (size_t)z * mat;
        const int r0 = (t9 & 15) * 64, c0 = (t9 >> 4) * 64;  // r over H, c over F
        float (*tile)[65] = (float(*)[65])smem;
        const int tc = tid & 63, tr = tid >> 6;              // tr 0..15
#pragma unroll
        for (int j = 0; j < 4; ++j)
            tile[tr + j * 16][tc] = ib[(size_t)(r0 + tr + j * 16) * F + c0 + tc];
        __syncthreads();
        const int c = tid >> 4;                              // 0..63
        const int r4 = (tid & 15) * 4;
        ushort4 o;
        o.x = f2bf(tile[r4 + 0][c]);
        o.y = f2bf(tile[r4 + 1][c]);
        o.z = f2bf(tile[r4 + 2][c]);
        o.w = f2bf(tile[r4 + 3][c]);
        *(ushort4*)(ob + (size_t)(c0 + c) * H + r0 + r4) = o;
        return;
    }

    // -------- deterministic compaction (token order) + inverse map --------
    const int e = blockIdx.x;
    const int lane = tid & 63, w = tid >> 6;
    int base = 0;
    for (int c = 0; c < T_TOK / 1024; ++c) {
        int t = c * 1024 + tid;
        int i1 = top_i[t * 2], i2 = top_i[t * 2 + 1];
        bool f1 = (i1 == e), f2 = (i2 == e);
        bool f = f1 || f2;
        unsigned long long m = __ballot(f);
        int mypos = __popcll(m & ((1ull << lane) - 1ull));
        if (lane == 0) wsums[w] = __popcll(m);
        __syncthreads();
        int wpre = 0, tot = 0;
#pragma unroll
        for (int i = 0; i < 16; ++i) { int s = wsums[i]; if (i < w) wpre += s; tot += s; }
        if (f) {
            int pos = base + wpre + mypos;
            btok[e * T_TOK + pos] = t;
            inv[t * 2 + (f1 ? 0 : 1)] = (e << 16) | pos;
        }
        base += tot;
        __syncthreads();
    }
    if (tid == 0) counts[e] = base;
}

// ============ FFN layer 1 (R4 structure) + w2 transpose at grid tail (R11-measured) ====
__global__ __launch_bounds__(256, 2) void ffn1_kernel(const unsigned short* __restrict__ xb,
                                                      const unsigned short* __restrict__ w1t,
                                                      const float* __restrict__ b1,
                                                      const float* __restrict__ w2,
                                                      unsigned short* __restrict__ w2t,
                                                      const int* __restrict__ counts,
                                                      const int* __restrict__ btok,
                                                      unsigned short* __restrict__ hbuf) {
    __shared__ __align__(16) char smem[65536];
    const int tid = threadIdx.x;

    if (blockIdx.x >= 8192) {
        // -------- w2 [F][H] -> w2t [H][F] (tail blocks; done before ffn2) --------
        int idx = blockIdx.x - 8192;
        int z = idx >> 9, t9 = idx & 511;
        const size_t mat = (size_t)F * H;
        transpose_tile(w2 + (size_t)z * mat, w2t + (size_t)z * mat,
                       F, H, (t9 >> 4) * 64, (t9 & 15) * 64, tid, smem);
        return;
    }

    // XCD-chunked decode: expert == XCD; within expert bx fastest
    const int orig = blockIdx.x;                 // 0..8191
    const int logical = (orig & 7) * 1024 + (orig >> 3);
    const int e = logical >> 10;
    const int rem = logical & 1023;
    const int by = rem >> 4;
    const int bx = rem & 15;
    const int cnt = counts[e];
    if (by * BM >= cnt) return;
    const int n0 = bx * BN;
    int off_e = 0;
#pragma unroll
    for (int i = 0; i < NE; ++i) off_e += (i < e) ? counts[i] : 0;

    const int lane = tid & 63, wid = tid >> 6;
    const int csrc = (lane & 7) ^ (lane >> 3);   // pre-swizzled source chunk
    const int rloc = lane >> 3;                  // row within 8-row segment

    int tokA[4];
#pragma unroll
    for (int i = 0; i < 4; ++i) {
        int r = wid * 32 + i * 8 + rloc;
        tokA[i] = btok[e * T_TOK + min(by * BM + r, cnt - 1)];
    }

    floatx4 acc[4][4];
#pragma unroll
    for (int i = 0; i < 4; ++i)
#pragma unroll
        for (int j = 0; j < 4; ++j)
#pragma unroll
            for (int r = 0; r < 4; ++r) acc[i][j][r] = 0.f;

    const int wm = (wid >> 1) * 64, wn = (wid & 1) * 64;

    auto stage = [&](int boff, int kt) {
        const int k0 = kt * BK;
#pragma unroll
        for (int i = 0; i < 4; ++i) {
            int seg = wid * 32 + i * 8;
            gload16(xb + (size_t)tokA[i] * H + k0 + csrc * 8, smem + boff + seg * 128);
            gload16(w1t + ((size_t)e * F + n0 + seg + rloc) * H + k0 + csrc * 8,
                    smem + boff + 16384 + seg * 128);
        }
    };

    const int NT = H / BK;  // 16
    stage(0, 0);
    int cur = 0;
    for (int kt = 0; kt < NT; ++kt) {
        const int boff = cur * 32768;
        __syncthreads();                         // drains vmcnt: buf[cur] ready
        if (kt + 1 < NT) stage(boff ^ 32768, kt + 1);  // async prefetch under compute
#pragma unroll
        for (int kk = 0; kk < 2; ++kk) {
            bf16x8 af[4], bfr[4];
#pragma unroll
            for (int i = 0; i < 4; ++i) {
                int rA = wm + i * 16 + (lane & 15);
                af[i] = *(const bf16x8*)(smem + boff + rA * 128 + (((kk * 4 + (lane >> 4)) ^ (rA & 7)) * 16));
                int rB = wn + i * 16 + (lane & 15);
                bfr[i] = *(const bf16x8*)(smem + boff + 16384 + rB * 128 + (((kk * 4 + (lane >> 4)) ^ (rB & 7)) * 16));
            }
#pragma unroll
            for (int i = 0; i < 4; ++i)
#pragma unroll
                for (int j = 0; j < 4; ++j)
                    acc[i][j] = __builtin_amdgcn_mfma_f32_16x16x32_bf16(af[i], bfr[j], acc[i][j], 0, 0, 0);
        }
        cur ^= 1;
    }

#pragma unroll
    for (int i = 0; i < 4; ++i) {
        int mrow = wm + i * 16 + (lane >> 4) * 4;
#pragma unroll
        for (int r = 0; r < 4; ++r) {
            int mg = by * BM + mrow + r;
            if (mg < cnt) {
                size_t hrow = (size_t)(off_e + mg) * F;
#pragma unroll
                for (int j = 0; j < 4; ++j) {
                    int ng = n0 + wn + j * 16 + (lane & 15);
                    float v = acc[i][j][r] + b1[e * F + ng];
                    hbuf[hrow + ng] = f2bf(fmaxf(v, 0.f));
                }
            }
        }
    }
}

// ============ FFN layer 2 (R4-proven): yc = h @ w2 + b2 ============
__global__ __launch_bounds__(256, 2) void ffn2_kernel(const unsigned short* __restrict__ hbuf,
                                                      const unsigned short* __restrict__ w2t,
                                                      const float* __restrict__ b2,
                                                      const int* __restrict__ counts,
                                                      unsigned short* __restrict__ yc) {
    const int orig = blockIdx.x;                 // grid = 4096
    const int logical = (orig & 7) * 512 + (orig >> 3);
    const int e = logical >> 9;
    const int rem = logical & 511;
    const int by = rem >> 3;
    const int bx = rem & 7;
    const int cnt = counts[e];
    if (by * BM >= cnt) return;
    const int n0 = bx * BN;
    int off_e = 0;
#pragma unroll
    for (int i = 0; i < NE; ++i) off_e += (i < e) ? counts[i] : 0;

    __shared__ __align__(16) char smem[65536];

    const int tid = threadIdx.x;
    const int lane = tid & 63, wid = tid >> 6;
    const int csrc = (lane & 7) ^ (lane >> 3);
    const int rloc = lane >> 3;

    int arow[4];
#pragma unroll
    for (int i = 0; i < 4; ++i) {
        int r = wid * 32 + i * 8 + rloc;
        arow[i] = off_e + min(by * BM + r, cnt - 1);
    }

    floatx4 acc[4][4];
#pragma unroll
    for (int i = 0; i < 4; ++i)
#pragma unroll
        for (int j = 0; j < 4; ++j)
#pragma unroll
            for (int r = 0; r < 4; ++r) acc[i][j][r] = 0.f;

    const int wm = (wid >> 1) * 64, wn = (wid & 1) * 64;

    auto stage = [&](int boff, int kt) {
        const int k0 = kt * BK;
#pragma unroll
        for (int i = 0; i < 4; ++i) {
            int seg = wid * 32 + i * 8;
            gload16(hbuf + (size_t)arow[i] * F + k0 + csrc * 8, smem + boff + seg * 128);
            gload16(w2t + ((size_t)e * H + n0 + seg + rloc) * F + k0 + csrc * 8,
                    smem + boff + 16384 + seg * 128);
        }
    };

    const int NT = F / BK;  // 32
    stage(0, 0);
    int cur = 0;
    for (int kt = 0; kt < NT; ++kt) {
        const int boff = cur * 32768;
        __syncthreads();
        if (kt + 1 < NT) stage(boff ^ 32768, kt + 1);
#pragma unroll
        for (int kk = 0; kk < 2; ++kk) {
            bf16x8 af[4], bfr[4];
#pragma unroll
            for (int i = 0; i < 4; ++i) {
                int rA = wm + i * 16 + (lane & 15);
                af[i] = *(const bf16x8*)(smem + boff + rA * 128 + (((kk * 4 + (lane >> 4)) ^ (rA & 7)) * 16));
                int rB = wn + i * 16 + (lane & 15);
                bfr[i] = *(const bf16x8*)(smem + boff + 16384 + rB * 128 + (((kk * 4 + (lane >> 4)) ^ (rB & 7)) * 16));
            }
#pragma unroll
            for (int i = 0; i < 4; ++i)
#pragma unroll
                for (int j = 0; j < 4; ++j)
                    acc[i][j] = __builtin_amdgcn_mfma_f32_16x16x32_bf16(af[i], bfr[j], acc[i][j], 0, 0, 0);
        }
        cur ^= 1;
    }

#pragma unroll
    for (int i = 0; i < 4; ++i) {
        int mrow = wm + i * 16 + (lane >> 4) * 4;
#pragma unroll
        for (int r = 0; r < 4; ++r) {
            int mg = by * BM + mrow + r;
            if (mg < cnt) {
                size_t yrow = (size_t)(off_e + mg) * H;
#pragma unroll
                for (int j = 0; j < 4; ++j) {
                    int ng = n0 + wn + j * 16 + (lane & 15);
                    yc[yrow + ng] = f2bf(acc[i][j][r] + b2[e * H + ng]);
                }
            }
        }
    }
}

// ---------------- combine: out[t] = w0*yc[slot0] + w1*yc[slot1], 4 tokens/block --------
__global__ __launch_bounds__(256) void combine_kernel(const unsigned short* __restrict__ yc,
                                                      const int* __restrict__ counts,
                                                      const int* __restrict__ inv,
                                                      const float* __restrict__ top_w,
                                                      float* __restrict__ out) {
    const int tid = threadIdx.x;
    int offs[NE];
    {
        int s = 0;
#pragma unroll
        for (int e = 0; e < NE; ++e) { offs[e] = s; s += counts[e]; }
    }
#pragma unroll
    for (int tk = 0; tk < 4; ++tk) {
        const int t = blockIdx.x * 4 + tk;
        int c0 = inv[2 * t], c1 = inv[2 * t + 1];
        float w0 = top_w[2 * t], w1 = top_w[2 * t + 1];
        size_t r0 = (size_t)(offs[c0 >> 16] + (c0 & 0xffff)) * H;
        size_t r1 = (size_t)(offs[c1 >> 16] + (c1 & 0xffff)) * H;
        int h = tid * 4;
        ushort4 a = *(const ushort4*)(yc + r0 + h);
        ushort4 b = *(const ushort4*)(yc + r1 + h);
        float4 o;
        o.x = w0 * bf2f(a.x) + w1 * bf2f(b.x);
        o.y = w0 * bf2f(a.y) + w1 * bf2f(b.y);
        o.z = w0 * bf2f(a.z) + w1 * bf2f(b.z);
        o.w = w0 * bf2f(a.w) + w1 * bf2f(b.w);
        *(float4*)(out + (size_t)t * H + h) = o;
    }
}

extern "C" void kernel_launch(void* const* d_in, const int* in_sizes, int n_in,
                              void* d_out, int out_size, void* d_ws, size_t ws_size,
                              hipStream_t stream) {
    (void)in_sizes; (void)n_in; (void)out_size; (void)ws_size;
    const float* x  = (const float*)d_in[0];
    const float* gw = (const float*)d_in[1];
    const float* gb = (const float*)d_in[2];
    const float* w1 = (const float*)d_in[3];
    const float* b1 = (const float*)d_in[4];
    const float* w2 = (const float*)d_in[5];
    const float* b2 = (const float*)d_in[6];
    float* out = (float*)d_out;

    char* ws = (char*)d_ws;
    unsigned short* w2t  = (unsigned short*)(ws);                        // 32 MB @ 0
    unsigned short* hbuf = (unsigned short*)(ws + (32ull << 20));        // 64 MB @ 32
    unsigned short* xb   = (unsigned short*)(ws + (96ull << 20));        // 16 MB @ 96
    unsigned short* w1t  = (unsigned short*)(ws + (112ull << 20));       // 32 MB @ 112 (ends 144)
    unsigned short* yc   = (unsigned short*)(ws + (96ull << 20));        // overlaps xb+w1t (dead after ffn1)
    char* small = ws + (144ull << 20);
    int*   btok   = (int*)(small);                                       // 256 KB
    int*   top_i  = (int*)(small + 0x80000);                             // 64 KB
    float* top_w  = (float*)(small + 0x90000);                           // 64 KB
    int*   inv    = (int*)(small + 0xA0000);                             // 64 KB
    int*   counts = (int*)(small + 0xB0000);

    gate_kernel<<<T_TOK, 256, 0, stream>>>(x, gw, gb, xb, top_i, top_w);
    compact_w1t_kernel<<<8 + 4096, 1024, 0, stream>>>(top_i, top_w, counts, btok, inv, w1, w1t);
    ffn1_kernel<<<8192 + 4096, 256, 0, stream>>>(xb, w1t, b1, w2, w2t, counts, btok, hbuf);
    ffn2_kernel<<<8 * 64 * NE, 256, 0, stream>>>(hbuf, w2t, b2, counts, yc);
    combine_kernel<<<T_TOK / 4, 256, 0, stream>>>(yc, counts, inv, top_w, out);
}